// Round 5
// baseline (660.865 us; speedup 1.0000x reference)
//
#include <hip/hip_runtime.h>

#define BB 8
#define MM 4096
#define EE 2048
#define DD 128

typedef _Float16 f16x8 __attribute__((ext_vector_type(8)));
typedef float    f32x4 __attribute__((ext_vector_type(4)));

// ---------------------------------------------------------------------------
// bitpack: inc (binary fp32) -> bit rows, bit i of word w = inc[w*32+i].
// Lane packs 32 consecutive floats (8 float4 loads, L1-resident line reuse);
// stores are fully coalesced 4 B/lane.
// ---------------------------------------------------------------------------
__global__ __launch_bounds__(256) void bitpack(const float* __restrict__ inc,
                                               unsigned* __restrict__ bits32)
{
    const size_t total32 = (size_t)BB * MM * EE / 32;   // 2,097,152
    size_t i  = (size_t)blockIdx.x * 256 + threadIdx.x;
    size_t st = (size_t)gridDim.x * 256;
    for (; i < total32; i += st){
        const float4* p = (const float4*)(inc + i * 32);
        unsigned u = 0;
        #pragma unroll
        for (int j = 0; j < 8; j++){
            float4 v = p[j];
            u |= (v.x != 0.f) ? (1u << (j * 4 + 0)) : 0u;
            u |= (v.y != 0.f) ? (1u << (j * 4 + 1)) : 0u;
            u |= (v.z != 0.f) ? (1u << (j * 4 + 2)) : 0u;
            u |= (v.w != 0.f) ? (1u << (j * 4 + 3)) : 0u;
        }
        bits32[i] = u;
    }
}

// ---------------------------------------------------------------------------
// bit_transpose: bits[m][e-bits] -> bitsT[e][m-bits], 64x64 ballot tiles.
// ---------------------------------------------------------------------------
__global__ __launch_bounds__(256) void bit_transpose(const unsigned long long* __restrict__ bits,
                                                     unsigned long long* __restrict__ bitsT)
{
    const int b = blockIdx.z;
    const int w = threadIdx.x >> 6;
    const int lane = threadIdx.x & 63;
    const int m0 = (blockIdx.y * 4 + w) * 64;
    const int e0 = blockIdx.x * 64;
    unsigned long long v = bits[((size_t)b * MM + m0 + lane) * (EE / 64) + (e0 >> 6)];
    unsigned long long mine = 0;
    #pragma unroll
    for (int e = 0; e < 64; e++){
        unsigned long long bal = __ballot((v >> e) & 1ull);
        if (lane == e) mine = bal;
    }
    bitsT[((size_t)b * EE + e0 + lane) * (MM / 64) + (m0 >> 6)] = mine;
}

// ---------------------------------------------------------------------------
// transpose_to16: src [R][C] fp32 -> dst [C][R] f16, batch = blockIdx.y.
// ---------------------------------------------------------------------------
__global__ __launch_bounds__(256) void transpose_to16(const float* __restrict__ src,
                                                      _Float16* __restrict__ dst,
                                                      int R, int C)
{
    __shared__ alignas(16) float tile[64 * 67];
    const int tilesC = C >> 6;
    const int r0 = (blockIdx.x / tilesC) << 6;
    const int c0 = (blockIdx.x % tilesC) << 6;
    const float* s = src + (size_t)blockIdx.y * R * C;
    _Float16*   d = dst + (size_t)blockIdx.y * R * C;
    const int t = threadIdx.x;
    #pragma unroll
    for (int i = 0; i < 4; i++){
        int idx = t + 256 * i;
        int r = idx >> 4, c4 = idx & 15;
        float4 v = *(const float4*)(s + (size_t)(r0 + r) * C + c0 + c4 * 4);
        tile[(c4 * 4 + 0) * 67 + r] = v.x;
        tile[(c4 * 4 + 1) * 67 + r] = v.y;
        tile[(c4 * 4 + 2) * 67 + r] = v.z;
        tile[(c4 * 4 + 3) * 67 + r] = v.w;
    }
    __syncthreads();
    #pragma unroll
    for (int i = 0; i < 2; i++){
        int idx = t + 256 * i;
        int row = idx >> 3, rb = idx & 7;
        f16x8 h;
        #pragma unroll
        for (int j = 0; j < 8; j++) h[j] = (_Float16)tile[row * 67 + rb * 8 + j];
        *(f16x8*)(d + (size_t)(c0 + row) * R + r0 + rb * 8) = h;
    }
}

// ---------------------------------------------------------------------------
// bitgemm<RF>: out[row][d] = sum_k bit(row,k) * dense[d][k]
//   RF = row-frags per wave; block tile = RF*64 rows x 128 d, BK = 64.
//   LDS ~34 KB (dense dbuf 2x16 KB + bits dbuf) -> 4 blocks/CU capacity;
//   launch >=512 blocks for 2 resident blocks/CU (cross-block overlap).
// ---------------------------------------------------------------------------
template<int RF>
__global__ __launch_bounds__(256) void bitgemm(const uint2* __restrict__ bitrows,
                                               const _Float16* __restrict__ dense,
                                               float* __restrict__ out,
                                               int R, int Ktot, int Kslice,
                                               unsigned sliceStride)
{
    constexpr int TR = RF * 64;                       // block rows
    constexpr int SM = (32768 + 2 * TR * 8) > 33792 ? (32768 + 2 * TR * 8) : 33792;
    __shared__ alignas(16) char smem[SM];

    const int b = blockIdx.y;
    const int row0 = blockIdx.x * TR;
    const int WB = Ktot >> 6;                         // uint2 (64-bit) words per bit-row
    const uint2* bp = bitrows + ((size_t)b * R + row0) * WB;
    const _Float16* dp = dense + (size_t)b * 128 * Ktot;
    float* op = out + (size_t)blockIdx.z * sliceStride + ((size_t)b * R + row0) * 128;
    const int kbase = blockIdx.z * Kslice;
    const int nchunk = Kslice >> 6;

    const int t = threadIdx.x, lane = t & 63, w = t >> 6;
    const int fr = lane & 15, q = lane >> 4, q8 = q * 8;

    f32x4 acc[RF][8] = {};
    uint4 rd[4];
    uint2 rb;

    auto loadg = [&](int kg){
        #pragma unroll
        for (int i = 0; i < 4; i++){
            int idx = t + 256 * i;
            int dd = idx >> 3, kb = idx & 7;
            rd[i] = *(const uint4*)(dp + (size_t)dd * Ktot + kg + kb * 8);
        }
        if (t < TR) rb = bp[(size_t)t * WB + (kg >> 6)];
    };
    auto stage = [&](int buf){
        _Float16* lD = (_Float16*)(smem + buf * 16384);
        uint2* lB = (uint2*)(smem + 32768 + buf * TR * 8);
        #pragma unroll
        for (int i = 0; i < 4; i++){
            int idx = t + 256 * i;
            int dd = idx >> 3, kb = idx & 7;
            *(uint4*)&lD[dd * 64 + ((kb ^ (dd & 7)) * 8)] = rd[i];
        }
        if (t < TR) lB[t] = rb;
    };
    auto compute = [&](int buf){
        const _Float16* lD = (const _Float16*)(smem + buf * 16384);
        const uint2* lB = (const uint2*)(smem + 32768 + buf * TR * 8);
        uint2 bw[RF];
        #pragma unroll
        for (int r = 0; r < RF; r++)
            bw[r] = lB[w * (RF * 16) + r * 16 + fr];  // q-broadcast, free
        #pragma unroll
        for (int h = 0; h < 2; h++){
            f16x8 af[RF];
            #pragma unroll
            for (int r = 0; r < RF; r++){
                unsigned word = h ? bw[r].y : bw[r].x;
                unsigned byte = (word >> q8) & 0xFFu;
                #pragma unroll
                for (int j = 0; j < 8; j++)
                    af[r][j] = (_Float16)(float)((byte >> j) & 1u);
            }
            #pragma unroll
            for (int c = 0; c < 8; c++){
                int drow = c * 16 + fr;
                f16x8 bf = *(const f16x8*)&lD[drow * 64 + (((h * 4 + q) ^ (drow & 7)) * 8)];
                #pragma unroll
                for (int r = 0; r < RF; r++)
                    acc[r][c] = __builtin_amdgcn_mfma_f32_16x16x32_f16(af[r], bf, acc[r][c], 0, 0, 0);
            }
        }
    };

    loadg(kbase);
    stage(0);
    __syncthreads();
    for (int c = 0; c < nchunk; c++){
        if (c + 1 < nchunk) loadg(kbase + (c + 1) * 64);   // global prefetch under compute
        compute(c & 1);
        if (c + 1 < nchunk) stage((c + 1) & 1);            // stage into other buffer
        __syncthreads();
    }

    // Epilogue: 64-row halves through LDS -> full-line float4 stores.
    float* sT = (float*)smem;
    #pragma unroll
    for (int hh = 0; hh < RF; hh++){
        __syncthreads();
        #pragma unroll
        for (int r = 0; r < RF; r++){
            int rowbase = w * (RF * 16) + r * 16;          // block-local row of this frag
            if (rowbase >= hh * 64 && rowbase < hh * 64 + 64){
                #pragma unroll
                for (int c = 0; c < 8; c++)
                    #pragma unroll
                    for (int reg = 0; reg < 4; reg++)
                        sT[(rowbase - hh * 64 + q * 4 + reg) * 132 + c * 16 + fr] = acc[r][c][reg];
            }
        }
        __syncthreads();
        #pragma unroll
        for (int i = 0; i < 8; i++){
            int idx = t + 256 * i;
            int lrow = idx >> 5, c4 = idx & 31;
            float4 v = *(const float4*)&sT[lrow * 132 + c4 * 4];
            *(float4*)(op + (size_t)(hh * 64 + lrow) * 128 + c4 * 4) = v;
        }
    }
}

// ---------------------------------------------------------------------------
// rowmm_sum4: A = p0+p1+p2+p3 (split-K partials); writes A -> aggOut and
// C = A @ W^T -> C. aggOut may alias p0 (each element read before written by
// the same thread; blocks own disjoint rows).
// ---------------------------------------------------------------------------
__global__ __launch_bounds__(256) void rowmm_sum4(const float* __restrict__ p,
                                                  const float* __restrict__ W,
                                                  float* aggOut,
                                                  float* __restrict__ C)
{
    __shared__ alignas(16) float lA[32][132];
    __shared__ alignas(16) float lW[64][140];
    const int t = threadIdx.x;
    const int row0 = blockIdx.x * 32;
    const float4* P4 = (const float4*)p;
    const float4* W4 = (const float4*)W;
    float4* A4 = (float4*)aggOut;
    const size_t SS = 2097152 / 4;                   // slice stride in float4

    #pragma unroll
    for (int i = 0; i < 4; i++){
        int idx = t + 256 * i;
        int r = idx >> 5, k4 = idx & 31;
        size_t gi = (size_t)(row0 + r) * 32 + k4;
        float4 a = P4[gi], b = P4[gi + SS], c = P4[gi + 2 * SS], d = P4[gi + 3 * SS];
        float4 s = make_float4(a.x + b.x + c.x + d.x, a.y + b.y + c.y + d.y,
                               a.z + b.z + c.z + d.z, a.w + b.w + c.w + d.w);
        *(float4*)&lA[r][k4 * 4] = s;
        A4[gi] = s;
    }
    const int qq = t >> 5;
    const int cc = t & 31;

    #pragma unroll
    for (int ph = 0; ph < 2; ph++){
        __syncthreads();
        #pragma unroll
        for (int i = 0; i < 8; i++){
            int idx = t + 256 * i;
            int c = idx >> 5, k4 = idx & 31;
            *(float4*)&lW[c][k4 * 4] = W4[(size_t)(ph * 64 + c) * 32 + k4];
        }
        __syncthreads();
        float s[4][2] = {};
        for (int k4 = 0; k4 < 32; k4++){
            float4 w0 = *(const float4*)&lW[cc][k4 * 4];
            float4 w1 = *(const float4*)&lW[cc + 32][k4 * 4];
            #pragma unroll
            for (int j = 0; j < 4; j++){
                float4 a = *(const float4*)&lA[qq + 8 * j][k4 * 4];
                s[j][0] += a.x * w0.x + a.y * w0.y + a.z * w0.z + a.w * w0.w;
                s[j][1] += a.x * w1.x + a.y * w1.y + a.z * w1.z + a.w * w1.w;
            }
        }
        #pragma unroll
        for (int j = 0; j < 4; j++){
            size_t ro = (size_t)(row0 + qq + 8 * j) * DD + ph * 64;
            C[ro + cc]      = s[j][0];
            C[ro + cc + 32] = s[j][1];
        }
    }
}

// ---------------------------------------------------------------------------
// rowmm: C[n,:] = A[n,:] @ W^T, fp32. In-place safe per block.
// ---------------------------------------------------------------------------
__global__ __launch_bounds__(256) void rowmm(const float* A,
                                             const float* __restrict__ W,
                                             float* C)
{
    __shared__ alignas(16) float lA[32][132];
    __shared__ alignas(16) float lW[64][140];
    const int t = threadIdx.x;
    const int row0 = blockIdx.x * 32;
    const float4* A4 = (const float4*)A;
    const float4* W4 = (const float4*)W;

    #pragma unroll
    for (int i = 0; i < 4; i++){
        int idx = t + 256 * i;
        int r = idx >> 5, k4 = idx & 31;
        *(float4*)&lA[r][k4 * 4] = A4[(size_t)(row0 + r) * 32 + k4];
    }
    const int qq = t >> 5;
    const int cc = t & 31;

    #pragma unroll
    for (int ph = 0; ph < 2; ph++){
        __syncthreads();
        #pragma unroll
        for (int i = 0; i < 8; i++){
            int idx = t + 256 * i;
            int c = idx >> 5, k4 = idx & 31;
            *(float4*)&lW[c][k4 * 4] = W4[(size_t)(ph * 64 + c) * 32 + k4];
        }
        __syncthreads();
        float s[4][2] = {};
        for (int k4 = 0; k4 < 32; k4++){
            float4 w0 = *(const float4*)&lW[cc][k4 * 4];
            float4 w1 = *(const float4*)&lW[cc + 32][k4 * 4];
            #pragma unroll
            for (int j = 0; j < 4; j++){
                float4 a = *(const float4*)&lA[qq + 8 * j][k4 * 4];
                s[j][0] += a.x * w0.x + a.y * w0.y + a.z * w0.z + a.w * w0.w;
                s[j][1] += a.x * w1.x + a.y * w1.y + a.z * w1.z + a.w * w1.w;
            }
        }
        #pragma unroll
        for (int j = 0; j < 4; j++){
            size_t ro = (size_t)(row0 + qq + 8 * j) * DD + ph * 64;
            C[ro + cc]      = s[j][0];
            C[ro + cc + 32] = s[j][1];
        }
    }
}

// ---------------------------------------------------------------------------
// wc_mm: Wc = eWp @ vWp  (128x128x128 fp32)
// ---------------------------------------------------------------------------
__global__ __launch_bounds__(256) void wc_mm(const float* __restrict__ eWp,
                                             const float* __restrict__ vWp,
                                             float* __restrict__ Wc)
{
    int i = blockIdx.x * 2 + (threadIdx.x >> 7);
    int j = threadIdx.x & 127;
    float acc = 0.f;
    for (int k = 0; k < 128; k++)
        acc += eWp[i * 128 + k] * vWp[k * 128 + j];
    Wc[i * 128 + j] = acc;
}

// ---------------------------------------------------------------------------
// Online softmax over e (two passes, coalesced).
// ---------------------------------------------------------------------------
__global__ __launch_bounds__(256) void sm_part(const float* __restrict__ eatt,
                                               float* __restrict__ part)
{
    const int b = blockIdx.x, slab = blockIdx.y;
    const int t = threadIdx.x;
    const int dl = t & 127, eh = t >> 7;
    const size_t base = (size_t)b * EE * DD + dl;
    const int e0 = slab * 256;
    float m = -1e30f;
    for (int s = 0; s < 128; s++)
        m = fmaxf(m, eatt[base + (size_t)(e0 + eh + 2 * s) * DD]);
    float l = 0.f;
    for (int s = 0; s < 128; s++)
        l += __expf(eatt[base + (size_t)(e0 + eh + 2 * s) * DD] - m);
    __shared__ float red[2][128][2];
    red[eh][dl][0] = m; red[eh][dl][1] = l;
    __syncthreads();
    if (t < 128){
        float m0 = red[0][t][0], l0 = red[0][t][1];
        float m1 = red[1][t][0], l1 = red[1][t][1];
        float M = fmaxf(m0, m1);
        float L = l0 * __expf(m0 - M) + l1 * __expf(m1 - M);
        float* pp = part + ((size_t)(b * 8 + slab) * DD + t) * 2;
        pp[0] = M; pp[1] = L;
    }
}

__global__ __launch_bounds__(256) void sm_apply(float* __restrict__ eatt,
                                                const float* __restrict__ agg,
                                                const float* __restrict__ part)
{
    const int b = blockIdx.x, sl = blockIdx.y;
    const int t = threadIdx.x;
    __shared__ float mv[128], iv[128];
    if (t < 128){
        float mbuf[8], lbuf[8];
        float M = -1e30f;
        #pragma unroll
        for (int s = 0; s < 8; s++){
            const float* pp = part + ((size_t)(b * 8 + s) * DD + t) * 2;
            mbuf[s] = pp[0]; lbuf[s] = pp[1];
            M = fmaxf(M, mbuf[s]);
        }
        float L = 0.f;
        #pragma unroll
        for (int s = 0; s < 8; s++) L += lbuf[s] * __expf(mbuf[s] - M);
        mv[t] = M; iv[t] = 1.f / L;
    }
    __syncthreads();
    const int dl = t & 127, eh = t >> 7;
    const size_t base = (size_t)b * EE * DD + dl;
    const int e0 = sl * 128;
    for (int s = 0; s < 64; s++){
        size_t ix = base + (size_t)(e0 + eh + 2 * s) * DD;
        eatt[ix] = agg[ix] * __expf(eatt[ix] - mv[dl]) * iv[dl];
    }
}

// ---------------------------------------------------------------------------
// Pipeline (layer recursion = fixed point; ec_Wa dead; associativity:
//   eatt = agg@vWa^T,  node = (inc@P) @ (eWp@vWp)^T):
//  1. bits = pack(inc); bitsT = bitT(bits); featT = T(feat) f16
//  2. p[0..3] = split-K bitgemm(bitsT, featT)
//  3. agg = sum p ; eatt = agg@vWa^T  (fused)
//  4. softmax -> P (in-place over eatt)
//  5. edge = P@vWp^T (OUT2) ; PT = T(P) f16 ; Wc = eWp@vWp
//  6. Q = bitgemm(bits, PT) -> node ; node = Q@Wc^T in-place (OUT1)
// ws (1 GiB): [0,8M)=bits; [8,16M)=bitsT->PT; [16,48M)=p0..p3 (agg over p0);
// [48M)=Wc.  d_out: node[0,8M)=featT; node[8,16M)=eatt/P; edge=part->edge.
// ---------------------------------------------------------------------------
extern "C" void kernel_launch(void* const* d_in, const int* in_sizes, int n_in,
                              void* d_out, int out_size, void* d_ws, size_t ws_size,
                              hipStream_t stream)
{
    const float* feat = (const float*)d_in[0];
    const float* inc  = (const float*)d_in[1];
    const float* vWa  = (const float*)d_in[2];
    const float* vWp  = (const float*)d_in[3];
    const float* eWp  = (const float*)d_in[6];

    float* node_out = (float*)d_out;
    float* edge_out = node_out + (size_t)BB * MM * DD;

    char* w = (char*)d_ws;
    unsigned* bits32 = (unsigned*)w;                                   // [0,8M)
    unsigned long long* bits = (unsigned long long*)w;
    unsigned long long* bitsT = (unsigned long long*)(w + ((size_t)8 << 20));
    _Float16* PT = (_Float16*)(w + ((size_t)8 << 20));                 // over dead bitsT
    float* pk = (float*)(w + ((size_t)16 << 20));                      // 4 x 8 MB partials
    float* agg = pk;                                                   // in-place over p0
    float* Wc = (float*)(w + ((size_t)48 << 20));

    _Float16* featT = (_Float16*)node_out;                             // node[0,8M)
    float* eattP = node_out + 2097152;                                 // node[8,16M)
    float* part  = edge_out;                                           // dead before edge

    dim3 blk(256);

    // 1. bit layouts + featT
    bitpack<<<dim3(4096), blk, 0, stream>>>(inc, bits32);
    bit_transpose<<<dim3(EE / 64, MM / 256, BB), blk, 0, stream>>>(bits, bitsT);
    transpose_to16<<<dim3((MM / 64) * (DD / 64), BB), blk, 0, stream>>>(feat, featT, MM, DD);
    // 2. split-K x4: p[z] = partial inc^T @ feat
    bitgemm<2><<<dim3(EE / 128, BB, 4), blk, 0, stream>>>(
        (const uint2*)bitsT, featT, pk, EE, MM, 1024, 2097152u);
    // 3. agg = sum p ; eatt = agg @ vWa^T
    rowmm_sum4<<<dim3(BB * EE / 32), blk, 0, stream>>>(pk, vWa, agg, eattP);
    // 4. P = agg * softmax_e(eatt)
    sm_part <<<dim3(BB, 8),  blk, 0, stream>>>(eattP, part);
    sm_apply<<<dim3(BB, 16), blk, 0, stream>>>(eattP, agg, part);
    // 5. edge = P @ vWp^T (OUT2); PT = f16(P^T); Wc = eWp @ vWp
    rowmm<<<dim3(BB * EE / 32), blk, 0, stream>>>(eattP, vWp, edge_out);
    transpose_to16<<<dim3((EE / 64) * (DD / 64), BB), blk, 0, stream>>>(eattP, PT, EE, DD);
    wc_mm<<<dim3(64), blk, 0, stream>>>(eWp, vWp, Wc);
    // 6. Q = inc @ P -> node ; node = Q @ Wc^T in-place (OUT1)
    bitgemm<1><<<dim3(MM / 64, BB, 1), blk, 0, stream>>>(
        (const uint2*)bits, PT, node_out, MM, EE, 2048, 0u);
    rowmm<<<dim3(BB * MM / 32), blk, 0, stream>>>(node_out, Wc, node_out);
}

// Round 6
// 618.673 us; speedup vs baseline: 1.0682x; 1.0682x over previous
//
#include <hip/hip_runtime.h>

#define BB 8
#define MM 4096
#define EE 2048
#define DD 128

typedef _Float16 f16x8 __attribute__((ext_vector_type(8)));
typedef float    f32x4 __attribute__((ext_vector_type(4)));

// ---------------------------------------------------------------------------
// pack_both: inc (binary fp32) -> bits[m][e-bit words] AND bitsT[e][m-bit
// words] in ONE 268-MB pass. Per wave: 64x64 tile; 64 coalesced 256-B row
// reads -> ballot over lanes(=e) gives bits word for row m (kept by lane m);
// then 64 ballots over lanes(=m) of the register words give bitsT.
// ---------------------------------------------------------------------------
__global__ __launch_bounds__(256) void pack_both(const float* __restrict__ inc,
                                                 unsigned long long* __restrict__ bits,
                                                 unsigned long long* __restrict__ bitsT)
{
    const int b  = blockIdx.z;
    const int w  = threadIdx.x >> 6;
    const int lane = threadIdx.x & 63;
    const int m0 = (blockIdx.y * 4 + w) * 64;
    const int e0 = blockIdx.x * 64;
    const float* ip = inc + ((size_t)b * MM + m0) * EE + e0;

    unsigned long long wbits = 0;
    #pragma unroll
    for (int mi = 0; mi < 64; mi++){
        float v = ip[(size_t)mi * EE + lane];
        unsigned long long bal = __ballot(v != 0.0f);
        wbits = (lane == mi) ? bal : wbits;
    }
    bits[((size_t)b * MM + m0 + lane) * (EE / 64) + (e0 >> 6)] = wbits;

    unsigned long long wT = 0;
    #pragma unroll
    for (int ei = 0; ei < 64; ei++){
        unsigned long long bal = __ballot((wbits >> ei) & 1ull);
        wT = (lane == ei) ? bal : wT;
    }
    bitsT[((size_t)b * EE + e0 + lane) * (MM / 64) + (m0 >> 6)] = wT;
}

// ---------------------------------------------------------------------------
// transpose_to16: src [R][C] fp32 -> dst [C][R] f16, batch = blockIdx.y.
// ---------------------------------------------------------------------------
__global__ __launch_bounds__(256) void transpose_to16(const float* __restrict__ src,
                                                      _Float16* __restrict__ dst,
                                                      int R, int C)
{
    __shared__ alignas(16) float tile[64 * 67];
    const int tilesC = C >> 6;
    const int r0 = (blockIdx.x / tilesC) << 6;
    const int c0 = (blockIdx.x % tilesC) << 6;
    const float* s = src + (size_t)blockIdx.y * R * C;
    _Float16*   d = dst + (size_t)blockIdx.y * R * C;
    const int t = threadIdx.x;
    #pragma unroll
    for (int i = 0; i < 4; i++){
        int idx = t + 256 * i;
        int r = idx >> 4, c4 = idx & 15;
        float4 v = *(const float4*)(s + (size_t)(r0 + r) * C + c0 + c4 * 4);
        tile[(c4 * 4 + 0) * 67 + r] = v.x;
        tile[(c4 * 4 + 1) * 67 + r] = v.y;
        tile[(c4 * 4 + 2) * 67 + r] = v.z;
        tile[(c4 * 4 + 3) * 67 + r] = v.w;
    }
    __syncthreads();
    #pragma unroll
    for (int i = 0; i < 2; i++){
        int idx = t + 256 * i;
        int row = idx >> 3, rb = idx & 7;
        f16x8 h;
        #pragma unroll
        for (int j = 0; j < 8; j++) h[j] = (_Float16)tile[row * 67 + rb * 8 + j];
        *(f16x8*)(d + (size_t)(c0 + row) * R + r0 + rb * 8) = h;
    }
}

// ---------------------------------------------------------------------------
// bitgemm1: p[z][row=e][d] = sum_{k in slice z} bitT(e,k) * featT[d][k]
// 64-row tiles, BK=64, dbuf LDS 33 KB (2 blocks/CU at grid 512).
// ---------------------------------------------------------------------------
__global__ __launch_bounds__(256) void bitgemm1(const uint2* __restrict__ bitrows,
                                                const _Float16* __restrict__ dense,
                                                float* __restrict__ out)
{
    __shared__ alignas(16) char smem[33792];
    const int b = blockIdx.y;
    const int row0 = blockIdx.x * 64;
    const int WB = MM >> 6;
    const uint2* bp = bitrows + ((size_t)b * EE + row0) * WB;
    const _Float16* dp = dense + (size_t)b * 128 * MM;
    float* op = out + (size_t)blockIdx.z * 2097152 + ((size_t)b * EE + row0) * 128;
    const int kbase = blockIdx.z * 2048;

    const int t = threadIdx.x, lane = t & 63, w = t >> 6;
    const int fr = lane & 15, q = lane >> 4, q8 = q * 8;

    f32x4 acc[8] = {};
    uint4 rd[4];
    uint2 rb;

    auto loadg = [&](int kg){
        #pragma unroll
        for (int i = 0; i < 4; i++){
            int idx = t + 256 * i;
            int dd = idx >> 3, kb = idx & 7;
            rd[i] = *(const uint4*)(dp + (size_t)dd * MM + kg + kb * 8);
        }
        if (t < 64) rb = bp[(size_t)t * WB + (kg >> 6)];
    };
    auto stage = [&](int buf){
        _Float16* lD = (_Float16*)(smem + buf * 16384);
        uint2* lB = (uint2*)(smem + 32768 + buf * 512);
        #pragma unroll
        for (int i = 0; i < 4; i++){
            int idx = t + 256 * i;
            int dd = idx >> 3, kb = idx & 7;
            *(uint4*)&lD[dd * 64 + ((kb ^ (dd & 7)) * 8)] = rd[i];
        }
        if (t < 64) lB[t] = rb;
    };
    auto compute = [&](int buf){
        const _Float16* lD = (const _Float16*)(smem + buf * 16384);
        const uint2* lB = (const uint2*)(smem + 32768 + buf * 512);
        uint2 bw = lB[w * 16 + fr];
        #pragma unroll
        for (int h = 0; h < 2; h++){
            unsigned word = h ? bw.y : bw.x;
            unsigned byte = (word >> q8) & 0xFFu;
            f16x8 af;
            #pragma unroll
            for (int j = 0; j < 8; j++)
                af[j] = ((byte >> j) & 1u) ? (_Float16)1.0f : (_Float16)0.0f;
            #pragma unroll
            for (int c = 0; c < 8; c++){
                int drow = c * 16 + fr;
                f16x8 bf = *(const f16x8*)&lD[drow * 64 + (((h * 4 + q) ^ (drow & 7)) * 8)];
                acc[c] = __builtin_amdgcn_mfma_f32_16x16x32_f16(af, bf, acc[c], 0, 0, 0);
            }
        }
    };

    loadg(kbase); stage(0); __syncthreads();
    for (int c = 0; c < 32; c++){
        if (c + 1 < 32) loadg(kbase + (c + 1) * 64);
        compute(c & 1);
        if (c + 1 < 32) stage((c + 1) & 1);
        __syncthreads();
    }
    float* sT = (float*)smem;
    #pragma unroll
    for (int c = 0; c < 8; c++)
        #pragma unroll
        for (int reg = 0; reg < 4; reg++)
            sT[(w * 16 + q * 4 + reg) * 132 + c * 16 + fr] = acc[c][reg];
    __syncthreads();
    #pragma unroll
    for (int i = 0; i < 8; i++){
        int idx = t + 256 * i;
        int lrow = idx >> 5, c4 = idx & 31;
        float4 v = *(const float4*)&sT[lrow * 132 + c4 * 4];
        *(float4*)(op + (size_t)lrow * 128 + c4 * 4) = v;
    }
}

// ---------------------------------------------------------------------------
// bitgemm2_fused: Q[m][j] = sum_e bit(m,e)*PT[j][e]; node[m][n] = sum_j
// Q[m][j]*Wc16[n][j] -- second stage fused via per-wave LDS Q (f16) + LDS Wc.
// ---------------------------------------------------------------------------
__global__ __launch_bounds__(256) void bitgemm2_fused(const uint2* __restrict__ bitrows,
                                                      const _Float16* __restrict__ PT,
                                                      const _Float16* __restrict__ Wc16,
                                                      float* __restrict__ node)
{
    __shared__ alignas(16) char smem[66560];   // [0,32K) dense dbuf; [32K,33K) bits; [33K,65K) Wc
    const int b = blockIdx.y;
    const int m0 = blockIdx.x * 64;
    const int WB = EE >> 6;
    const uint2* bp = bitrows + ((size_t)b * MM + m0) * WB;
    const _Float16* dp = PT + (size_t)b * 128 * EE;
    float* op = node + ((size_t)b * MM + m0) * 128;

    const int t = threadIdx.x, lane = t & 63, w = t >> 6;
    const int fr = lane & 15, q = lane >> 4, q8 = q * 8;

    _Float16* lWc = (_Float16*)(smem + 33792);
    #pragma unroll
    for (int i = 0; i < 8; i++){
        int idx = t + 256 * i;
        int n = idx >> 4, kb = idx & 15;
        *(uint4*)&lWc[n * 128 + ((kb ^ (n & 7)) * 8)] =
            *(const uint4*)(Wc16 + (size_t)n * 128 + kb * 8);
    }

    f32x4 acc[8] = {};
    uint4 rd[4];
    uint2 rb;

    auto loadg = [&](int kg){
        #pragma unroll
        for (int i = 0; i < 4; i++){
            int idx = t + 256 * i;
            int dd = idx >> 3, kb = idx & 7;
            rd[i] = *(const uint4*)(dp + (size_t)dd * EE + kg + kb * 8);
        }
        if (t < 64) rb = bp[(size_t)t * WB + (kg >> 6)];
    };
    auto stage = [&](int buf){
        _Float16* lD = (_Float16*)(smem + buf * 16384);
        uint2* lB = (uint2*)(smem + 32768 + buf * 512);
        #pragma unroll
        for (int i = 0; i < 4; i++){
            int idx = t + 256 * i;
            int dd = idx >> 3, kb = idx & 7;
            *(uint4*)&lD[dd * 64 + ((kb ^ (dd & 7)) * 8)] = rd[i];
        }
        if (t < 64) lB[t] = rb;
    };
    auto compute = [&](int buf){
        const _Float16* lD = (const _Float16*)(smem + buf * 16384);
        const uint2* lB = (const uint2*)(smem + 32768 + buf * 512);
        uint2 bw = lB[w * 16 + fr];
        #pragma unroll
        for (int h = 0; h < 2; h++){
            unsigned word = h ? bw.y : bw.x;
            unsigned byte = (word >> q8) & 0xFFu;
            f16x8 af;
            #pragma unroll
            for (int j = 0; j < 8; j++)
                af[j] = ((byte >> j) & 1u) ? (_Float16)1.0f : (_Float16)0.0f;
            #pragma unroll
            for (int c = 0; c < 8; c++){
                int drow = c * 16 + fr;
                f16x8 bf = *(const f16x8*)&lD[drow * 64 + (((h * 4 + q) ^ (drow & 7)) * 8)];
                acc[c] = __builtin_amdgcn_mfma_f32_16x16x32_f16(af, bf, acc[c], 0, 0, 0);
            }
        }
    };

    loadg(0); stage(0); __syncthreads();
    for (int c = 0; c < 32; c++){
        if (c + 1 < 32) loadg((c + 1) * 64);
        compute(c & 1);
        if (c + 1 < 32) stage((c + 1) & 1);
        __syncthreads();
    }

    // Phase 2: Q (f16, per-wave-private rows) @ Wc^T via MFMA.
    _Float16* sQ = (_Float16*)smem;            // [64][128] XOR, rows w*16.. private per wave
    #pragma unroll
    for (int c = 0; c < 8; c++){
        #pragma unroll
        for (int reg = 0; reg < 4; reg++){
            int row = w * 16 + q * 4 + reg;
            int col = c * 16 + fr;
            sQ[row * 128 + (((col >> 3) ^ (row & 7)) * 8) + (col & 7)] = (_Float16)acc[c][reg];
        }
    }
    f32x4 acc2[8] = {};
    #pragma unroll
    for (int kk = 0; kk < 4; kk++){
        int arow = w * 16 + fr;
        f16x8 a2 = *(const f16x8*)&sQ[arow * 128 + (((kk * 4 + q) ^ (arow & 7)) * 8)];
        #pragma unroll
        for (int c = 0; c < 8; c++){
            int n = c * 16 + fr;
            f16x8 b2 = *(const f16x8*)&lWc[n * 128 + (((kk * 4 + q) ^ (n & 7)) * 8)];
            acc2[c] = __builtin_amdgcn_mfma_f32_16x16x32_f16(a2, b2, acc2[c], 0, 0, 0);
        }
    }
    __syncthreads();
    float* sD = (float*)smem;                  // [64][132]
    #pragma unroll
    for (int c = 0; c < 8; c++)
        #pragma unroll
        for (int reg = 0; reg < 4; reg++)
            sD[(w * 16 + q * 4 + reg) * 132 + c * 16 + fr] = acc2[c][reg];
    __syncthreads();
    #pragma unroll
    for (int i = 0; i < 8; i++){
        int idx = t + 256 * i;
        int lrow = idx >> 5, c4 = idx & 31;
        float4 v = *(const float4*)&sD[lrow * 132 + c4 * 4];
        *(float4*)(op + (size_t)lrow * 128 + c4 * 4) = v;
    }
}

// ---------------------------------------------------------------------------
// rowmm_sum2: A = p0+p1; writes A -> aggOut (aliases p0, safe) and
// C = A @ W^T -> C.
// ---------------------------------------------------------------------------
__global__ __launch_bounds__(256) void rowmm_sum2(const float* __restrict__ p,
                                                  const float* __restrict__ W,
                                                  float* aggOut,
                                                  float* __restrict__ C)
{
    __shared__ alignas(16) float lA[32][132];
    __shared__ alignas(16) float lW[64][140];
    const int t = threadIdx.x;
    const int row0 = blockIdx.x * 32;
    const float4* P4 = (const float4*)p;
    const float4* W4 = (const float4*)W;
    float4* A4 = (float4*)aggOut;
    const size_t SS = 2097152 / 4;

    #pragma unroll
    for (int i = 0; i < 4; i++){
        int idx = t + 256 * i;
        int r = idx >> 5, k4 = idx & 31;
        size_t gi = (size_t)(row0 + r) * 32 + k4;
        float4 a = P4[gi], b = P4[gi + SS];
        float4 s = make_float4(a.x + b.x, a.y + b.y, a.z + b.z, a.w + b.w);
        *(float4*)&lA[r][k4 * 4] = s;
        A4[gi] = s;
    }
    const int qq = t >> 5, cc = t & 31;

    #pragma unroll
    for (int ph = 0; ph < 2; ph++){
        __syncthreads();
        #pragma unroll
        for (int i = 0; i < 8; i++){
            int idx = t + 256 * i;
            int c = idx >> 5, k4 = idx & 31;
            *(float4*)&lW[c][k4 * 4] = W4[(size_t)(ph * 64 + c) * 32 + k4];
        }
        __syncthreads();
        float s[4][2] = {};
        for (int k4 = 0; k4 < 32; k4++){
            float4 w0 = *(const float4*)&lW[cc][k4 * 4];
            float4 w1 = *(const float4*)&lW[cc + 32][k4 * 4];
            #pragma unroll
            for (int j = 0; j < 4; j++){
                float4 a = *(const float4*)&lA[qq + 8 * j][k4 * 4];
                s[j][0] += a.x * w0.x + a.y * w0.y + a.z * w0.z + a.w * w0.w;
                s[j][1] += a.x * w1.x + a.y * w1.y + a.z * w1.z + a.w * w1.w;
            }
        }
        #pragma unroll
        for (int j = 0; j < 4; j++){
            size_t ro = (size_t)(row0 + qq + 8 * j) * DD + ph * 64;
            C[ro + cc]      = s[j][0];
            C[ro + cc + 32] = s[j][1];
        }
    }
}

// ---------------------------------------------------------------------------
// rowmm: C[n,:] = A[n,:] @ W^T, fp32.
// ---------------------------------------------------------------------------
__global__ __launch_bounds__(256) void rowmm(const float* A,
                                             const float* __restrict__ W,
                                             float* C)
{
    __shared__ alignas(16) float lA[32][132];
    __shared__ alignas(16) float lW[64][140];
    const int t = threadIdx.x;
    const int row0 = blockIdx.x * 32;
    const float4* A4 = (const float4*)A;
    const float4* W4 = (const float4*)W;

    #pragma unroll
    for (int i = 0; i < 4; i++){
        int idx = t + 256 * i;
        int r = idx >> 5, k4 = idx & 31;
        *(float4*)&lA[r][k4 * 4] = A4[(size_t)(row0 + r) * 32 + k4];
    }
    const int qq = t >> 5, cc = t & 31;

    #pragma unroll
    for (int ph = 0; ph < 2; ph++){
        __syncthreads();
        #pragma unroll
        for (int i = 0; i < 8; i++){
            int idx = t + 256 * i;
            int c = idx >> 5, k4 = idx & 31;
            *(float4*)&lW[c][k4 * 4] = W4[(size_t)(ph * 64 + c) * 32 + k4];
        }
        __syncthreads();
        float s[4][2] = {};
        for (int k4 = 0; k4 < 32; k4++){
            float4 w0 = *(const float4*)&lW[cc][k4 * 4];
            float4 w1 = *(const float4*)&lW[cc + 32][k4 * 4];
            #pragma unroll
            for (int j = 0; j < 4; j++){
                float4 a = *(const float4*)&lA[qq + 8 * j][k4 * 4];
                s[j][0] += a.x * w0.x + a.y * w0.y + a.z * w0.z + a.w * w0.w;
                s[j][1] += a.x * w1.x + a.y * w1.y + a.z * w1.z + a.w * w1.w;
            }
        }
        #pragma unroll
        for (int j = 0; j < 4; j++){
            size_t ro = (size_t)(row0 + qq + 8 * j) * DD + ph * 64;
            C[ro + cc]      = s[j][0];
            C[ro + cc + 32] = s[j][1];
        }
    }
}

// ---------------------------------------------------------------------------
// wc_mm16: Wc16 = f16(eWp @ vWp)  (128x128x128)
// ---------------------------------------------------------------------------
__global__ __launch_bounds__(256) void wc_mm16(const float* __restrict__ eWp,
                                               const float* __restrict__ vWp,
                                               _Float16* __restrict__ Wc16)
{
    int i = blockIdx.x * 2 + (threadIdx.x >> 7);
    int j = threadIdx.x & 127;
    float acc = 0.f;
    for (int k = 0; k < 128; k++)
        acc += eWp[i * 128 + k] * vWp[k * 128 + j];
    Wc16[i * 128 + j] = (_Float16)acc;
}

// ---------------------------------------------------------------------------
// Online softmax over e (two passes, coalesced).
// ---------------------------------------------------------------------------
__global__ __launch_bounds__(256) void sm_part(const float* __restrict__ eatt,
                                               float* __restrict__ part)
{
    const int b = blockIdx.x, slab = blockIdx.y;
    const int t = threadIdx.x;
    const int dl = t & 127, eh = t >> 7;
    const size_t base = (size_t)b * EE * DD + dl;
    const int e0 = slab * 256;
    float m = -1e30f;
    for (int s = 0; s < 128; s++)
        m = fmaxf(m, eatt[base + (size_t)(e0 + eh + 2 * s) * DD]);
    float l = 0.f;
    for (int s = 0; s < 128; s++)
        l += __expf(eatt[base + (size_t)(e0 + eh + 2 * s) * DD] - m);
    __shared__ float red[2][128][2];
    red[eh][dl][0] = m; red[eh][dl][1] = l;
    __syncthreads();
    if (t < 128){
        float m0 = red[0][t][0], l0 = red[0][t][1];
        float m1 = red[1][t][0], l1 = red[1][t][1];
        float M = fmaxf(m0, m1);
        float L = l0 * __expf(m0 - M) + l1 * __expf(m1 - M);
        float* pp = part + ((size_t)(b * 8 + slab) * DD + t) * 2;
        pp[0] = M; pp[1] = L;
    }
}

__global__ __launch_bounds__(256) void sm_apply(float* __restrict__ eatt,
                                                const float* __restrict__ agg,
                                                const float* __restrict__ part)
{
    const int b = blockIdx.x, sl = blockIdx.y;
    const int t = threadIdx.x;
    __shared__ float mv[128], iv[128];
    if (t < 128){
        float mbuf[8], lbuf[8];
        float M = -1e30f;
        #pragma unroll
        for (int s = 0; s < 8; s++){
            const float* pp = part + ((size_t)(b * 8 + s) * DD + t) * 2;
            mbuf[s] = pp[0]; lbuf[s] = pp[1];
            M = fmaxf(M, mbuf[s]);
        }
        float L = 0.f;
        #pragma unroll
        for (int s = 0; s < 8; s++) L += lbuf[s] * __expf(mbuf[s] - M);
        mv[t] = M; iv[t] = 1.f / L;
    }
    __syncthreads();
    const int dl = t & 127, eh = t >> 7;
    const size_t base = (size_t)b * EE * DD + dl;
    const int e0 = sl * 128;
    for (int s = 0; s < 64; s++){
        size_t ix = base + (size_t)(e0 + eh + 2 * s) * DD;
        eatt[ix] = agg[ix] * __expf(eatt[ix] - mv[dl]) * iv[dl];
    }
}

// ---------------------------------------------------------------------------
// Pipeline (layer recursion = fixed point; ec_Wa dead):
//  1. pack_both: bits + bitsT (one pass)       2. featT = T(feat) f16
//  3. Wc16 = f16(eWp@vWp)                      4. p0,p1 = splitK bitgemm1
//  5. agg = p0+p1; eatt = agg@vWa^T (fused)    6. softmax -> P (in-place)
//  7. edge = P@vWp^T (OUT2); PT = T(P) f16     8. node = fused bitgemm2 (OUT1)
// ws: [0,8M)=bits; [8,16M)=bitsT->PT; [16,32M)=p0,p1 (agg over p0); [32M)=Wc16.
// d_out: node[0,8M)=featT; node[8,16M)=eatt/P; edge=part->edge.
// ---------------------------------------------------------------------------
extern "C" void kernel_launch(void* const* d_in, const int* in_sizes, int n_in,
                              void* d_out, int out_size, void* d_ws, size_t ws_size,
                              hipStream_t stream)
{
    const float* feat = (const float*)d_in[0];
    const float* inc  = (const float*)d_in[1];
    const float* vWa  = (const float*)d_in[2];
    const float* vWp  = (const float*)d_in[3];
    const float* eWp  = (const float*)d_in[6];

    float* node_out = (float*)d_out;
    float* edge_out = node_out + (size_t)BB * MM * DD;

    char* w = (char*)d_ws;
    unsigned long long* bits  = (unsigned long long*)w;
    unsigned long long* bitsT = (unsigned long long*)(w + ((size_t)8 << 20));
    _Float16* PT = (_Float16*)(w + ((size_t)8 << 20));        // over dead bitsT
    float* pk  = (float*)(w + ((size_t)16 << 20));            // p0,p1 (8 MB each)
    float* agg = pk;                                          // over p0
    _Float16* Wc16 = (_Float16*)(w + ((size_t)32 << 20));

    _Float16* featT = (_Float16*)node_out;                    // node[0,8M)
    float* eattP = node_out + 2097152;                        // node[8,16M)
    float* part  = edge_out;                                  // dead before edge

    dim3 blk(256);

    // 1. bits + bitsT in one pass
    pack_both<<<dim3(EE / 64, MM / 256, BB), blk, 0, stream>>>(inc, bits, bitsT);
    // 2. featT = f16(feat^T); 3. Wc16
    transpose_to16<<<dim3((MM / 64) * (DD / 64), BB), blk, 0, stream>>>(feat, featT, MM, DD);
    wc_mm16<<<dim3(64), blk, 0, stream>>>(eWp, vWp, Wc16);
    // 4. split-K x2: p[z] = partial inc^T @ feat
    bitgemm1<<<dim3(EE / 64, BB, 2), blk, 0, stream>>>((const uint2*)bitsT, featT, pk);
    // 5. agg = p0+p1 ; eatt = agg @ vWa^T
    rowmm_sum2<<<dim3(BB * EE / 32), blk, 0, stream>>>(pk, vWa, agg, eattP);
    // 6. P = agg * softmax_e(eatt)
    sm_part <<<dim3(BB, 8),  blk, 0, stream>>>(eattP, part);
    sm_apply<<<dim3(BB, 16), blk, 0, stream>>>(eattP, agg, part);
    // 7. edge = P @ vWp^T (OUT2); PT = f16(P^T)
    rowmm<<<dim3(BB * EE / 32), blk, 0, stream>>>(eattP, vWp, edge_out);
    transpose_to16<<<dim3((EE / 64) * (DD / 64), BB), blk, 0, stream>>>(eattP, PT, EE, DD);
    // 8. node = (inc@P) @ Wc^T fused (OUT1)
    bitgemm2_fused<<<dim3(MM / 64, BB), blk, 0, stream>>>((const uint2*)bits, PT, Wc16, node_out);
}

// Round 7
// 564.891 us; speedup vs baseline: 1.1699x; 1.0952x over previous
//
#include <hip/hip_runtime.h>

#define BB 8
#define MM 4096
#define EE 2048
#define DD 128

typedef _Float16 f16x8 __attribute__((ext_vector_type(8)));
typedef float    f32x4 __attribute__((ext_vector_type(4)));

// ---------------------------------------------------------------------------
// transpose_to16: src [R][C] fp32 -> dst [C][R] f16, batch = blockIdx.y.
// ---------------------------------------------------------------------------
__global__ __launch_bounds__(256) void transpose_to16(const float* __restrict__ src,
                                                      _Float16* __restrict__ dst,
                                                      int R, int C)
{
    __shared__ alignas(16) float tile[64 * 67];
    const int tilesC = C >> 6;
    const int r0 = (blockIdx.x / tilesC) << 6;
    const int c0 = (blockIdx.x % tilesC) << 6;
    const float* s = src + (size_t)blockIdx.y * R * C;
    _Float16*   d = dst + (size_t)blockIdx.y * R * C;
    const int t = threadIdx.x;
    #pragma unroll
    for (int i = 0; i < 4; i++){
        int idx = t + 256 * i;
        int r = idx >> 4, c4 = idx & 15;
        float4 v = *(const float4*)(s + (size_t)(r0 + r) * C + c0 + c4 * 4);
        tile[(c4 * 4 + 0) * 67 + r] = v.x;
        tile[(c4 * 4 + 1) * 67 + r] = v.y;
        tile[(c4 * 4 + 2) * 67 + r] = v.z;
        tile[(c4 * 4 + 3) * 67 + r] = v.w;
    }
    __syncthreads();
    #pragma unroll
    for (int i = 0; i < 2; i++){
        int idx = t + 256 * i;
        int row = idx >> 3, rb = idx & 7;
        f16x8 h;
        #pragma unroll
        for (int j = 0; j < 8; j++) h[j] = (_Float16)tile[row * 67 + rb * 8 + j];
        *(f16x8*)(d + (size_t)(c0 + row) * R + r0 + rb * 8) = h;
    }
}

// ---------------------------------------------------------------------------
// fused_gemm1: the single 268-MB inc pass does everything:
//   - stages inc fp32 tiles, double-ballot packs in-wave (64x64 bit tiles)
//   - MFMA A-frags (e-rows, k=m bits) straight from per-wave bitsT words
//   - emits bitsX[b][e-word][m] (word-transposed layout: contiguous writes
//     here, contiguous per-chunk reads in bitgemm2)
//   - accumulates p[z] = split-K partial of agg = inc^T @ feat
// Tile 256 e x 128 d, BK = 64 m, split-K x4 (1024 m each).
// Grid (EE/256=8, BB, 4) = 256 blocks = 1/CU; HBM-bound by design:
// per chunk/CU 64 KB inc @ ~10 B/cyc = 6.2K cyc >> ~1.7K cyc VALU+MFMA+LDS.
// ---------------------------------------------------------------------------
__global__ __launch_bounds__(256, 1) void fused_gemm1(const float* __restrict__ inc,
                                                      const _Float16* __restrict__ featT,
                                                      unsigned long long* __restrict__ bitsX,
                                                      float* __restrict__ p)
{
    __shared__ alignas(16) char smem[36864];   // [0,32K) dense dbuf; [32K,36K) bitsT dbuf

    const int x = blockIdx.x;                  // e-super-block (256 e)
    const int b = blockIdx.y;
    const int z = blockIdx.z;                  // K-slice (1024 m)
    const int t = threadIdx.x, lane = t & 63, w = t >> 6;
    const int fr = lane & 15, q = lane >> 4, q8 = q * 8;

    const int e0 = x * 256;
    const int ew0 = e0 + w * 64;               // this wave's 64-e column group
    const _Float16* dp = featT + (size_t)b * 128 * MM;
    const float* ip = inc + (size_t)b * MM * EE + ew0 + lane;
    unsigned long long* bxp = bitsX + ((size_t)b * 32 + (x * 4 + w)) * MM;

    f32x4 acc[4][8] = {};                      // 64 e-rows x 128 d per wave
    uint4 rd[4];
    float val[64];

    auto loadg = [&](int k0){
        #pragma unroll
        for (int i = 0; i < 4; i++){
            int idx = t + 256 * i;
            int dd = idx >> 3, kb = idx & 7;
            rd[i] = *(const uint4*)(dp + (size_t)dd * MM + k0 + kb * 8);
        }
        const float* rp = ip + (size_t)k0 * EE;
        #pragma unroll
        for (int j = 0; j < 64; j++) val[j] = rp[(size_t)j * EE];
    };
    auto stage = [&](int buf, int k0){
        _Float16* lD = (_Float16*)(smem + buf * 16384);
        unsigned long long* lBits = (unsigned long long*)(smem + 32768 + buf * 2048);
        #pragma unroll
        for (int i = 0; i < 4; i++){
            int idx = t + 256 * i;
            int dd = idx >> 3, kb = idx & 7;
            *(uint4*)&lD[dd * 64 + ((kb ^ (dd & 7)) * 8)] = rd[i];
        }
        // pack: lane j keeps e-bit word of row k0+j
        unsigned long long wbits = 0;
        #pragma unroll
        for (int j = 0; j < 64; j++){
            unsigned long long bal = __ballot(val[j] != 0.0f);
            wbits = (lane == j) ? bal : wbits;
        }
        bxp[k0 + lane] = wbits;                // contiguous 512 B per wave
        // transpose: lane ei keeps m-bit word of e-col ew0+ei
        unsigned long long wT = 0;
        #pragma unroll
        for (int ei = 0; ei < 64; ei++){
            unsigned long long bal = __ballot((wbits >> ei) & 1ull);
            wT = (lane == ei) ? bal : wT;
        }
        lBits[w * 64 + lane] = wT;
    };
    auto compute = [&](int buf){
        const _Float16* lD = (const _Float16*)(smem + buf * 16384);
        const uint2* lBits = (const uint2*)(smem + 32768 + buf * 2048);
        uint2 bw[4];
        f16x8 af[4][2];
        #pragma unroll
        for (int s = 0; s < 4; s++) bw[s] = lBits[w * 64 + s * 16 + fr];
        #pragma unroll
        for (int s = 0; s < 4; s++)
            #pragma unroll
            for (int h = 0; h < 2; h++){
                unsigned word = h ? bw[s].y : bw[s].x;
                unsigned byte = (word >> q8) & 0xFFu;
                #pragma unroll
                for (int j = 0; j < 8; j++)
                    af[s][h][j] = ((byte >> j) & 1u) ? (_Float16)1.0f : (_Float16)0.0f;
            }
        #pragma unroll
        for (int h = 0; h < 2; h++)
            #pragma unroll
            for (int c = 0; c < 8; c++){
                int drow = c * 16 + fr;
                f16x8 bf = *(const f16x8*)&lD[drow * 64 + (((h * 4 + q) ^ (drow & 7)) * 8)];
                #pragma unroll
                for (int s = 0; s < 4; s++)
                    acc[s][c] = __builtin_amdgcn_mfma_f32_16x16x32_f16(af[s][h], bf, acc[s][c], 0, 0, 0);
            }
    };

    const int kbase = z * 1024;
    loadg(kbase); stage(0, kbase); __syncthreads();
    for (int c = 0; c < 16; c++){
        if (c + 1 < 16) loadg(kbase + (c + 1) * 64);   // prefetch under compute
        compute(c & 1);
        if (c + 1 < 16) stage((c + 1) & 1, kbase + (c + 1) * 64);
        __syncthreads();
    }

    // Epilogue: 4 phases; wave ph stages its 64 e-rows, all copy out full lines.
    float* sT = (float*)smem;
    float* op = p + (size_t)z * 2097152 + ((size_t)b * EE + e0) * 128;
    for (int ph = 0; ph < 4; ph++){
        __syncthreads();
        if (w == ph){
            #pragma unroll
            for (int s = 0; s < 4; s++)
                #pragma unroll
                for (int c = 0; c < 8; c++)
                    #pragma unroll
                    for (int reg = 0; reg < 4; reg++)
                        sT[(s * 16 + q * 4 + reg) * 132 + c * 16 + fr] = acc[s][c][reg];
        }
        __syncthreads();
        #pragma unroll
        for (int i = 0; i < 8; i++){
            int idx = t + 256 * i;
            int lrow = idx >> 5, c4 = idx & 31;
            float4 v = *(const float4*)&sT[lrow * 132 + c4 * 4];
            *(float4*)(op + (size_t)(ph * 64 + lrow) * 128 + c4 * 4) = v;
        }
    }
}

// ---------------------------------------------------------------------------
// bitgemm2_fused: Q[m][j] = sum_e bit(m,e)*PT[j][e]; node[m][n] = sum_j
// Q[m][j]*Wc16[n][j]. bitsX layout -> contiguous per-chunk bit-word loads.
// ---------------------------------------------------------------------------
__global__ __launch_bounds__(256) void bitgemm2_fused(const unsigned long long* __restrict__ bitsX,
                                                      const _Float16* __restrict__ PT,
                                                      const _Float16* __restrict__ Wc16,
                                                      float* __restrict__ node)
{
    __shared__ alignas(16) char smem[66560];   // [0,32K) dense dbuf; [32K,33K) bits; [33K,65K) Wc
    const int b = blockIdx.y;
    const int m0 = blockIdx.x * 64;
    const unsigned long long* bxp = bitsX + (size_t)b * 32 * MM;
    const _Float16* dp = PT + (size_t)b * 128 * EE;
    float* op = node + ((size_t)b * MM + m0) * 128;

    const int t = threadIdx.x, lane = t & 63, w = t >> 6;
    const int fr = lane & 15, q = lane >> 4, q8 = q * 8;

    _Float16* lWc = (_Float16*)(smem + 33792);
    #pragma unroll
    for (int i = 0; i < 8; i++){
        int idx = t + 256 * i;
        int n = idx >> 4, kb = idx & 15;
        *(uint4*)&lWc[n * 128 + ((kb ^ (n & 7)) * 8)] =
            *(const uint4*)(Wc16 + (size_t)n * 128 + kb * 8);
    }

    f32x4 acc[8] = {};
    uint4 rd[4];
    unsigned long long rb;

    auto loadg = [&](int kg){
        #pragma unroll
        for (int i = 0; i < 4; i++){
            int idx = t + 256 * i;
            int dd = idx >> 3, kb = idx & 7;
            rd[i] = *(const uint4*)(dp + (size_t)dd * EE + kg + kb * 8);
        }
        if (t < 64) rb = bxp[(size_t)(kg >> 6) * MM + m0 + t];   // contiguous
    };
    auto stage = [&](int buf){
        _Float16* lD = (_Float16*)(smem + buf * 16384);
        unsigned long long* lB = (unsigned long long*)(smem + 32768 + buf * 512);
        #pragma unroll
        for (int i = 0; i < 4; i++){
            int idx = t + 256 * i;
            int dd = idx >> 3, kb = idx & 7;
            *(uint4*)&lD[dd * 64 + ((kb ^ (dd & 7)) * 8)] = rd[i];
        }
        if (t < 64) lB[t] = rb;
    };
    auto compute = [&](int buf){
        const _Float16* lD = (const _Float16*)(smem + buf * 16384);
        const uint2* lB = (const uint2*)(smem + 32768 + buf * 512);
        uint2 bw = lB[w * 16 + fr];
        #pragma unroll
        for (int h = 0; h < 2; h++){
            unsigned word = h ? bw.y : bw.x;
            unsigned byte = (word >> q8) & 0xFFu;
            f16x8 af;
            #pragma unroll
            for (int j = 0; j < 8; j++)
                af[j] = ((byte >> j) & 1u) ? (_Float16)1.0f : (_Float16)0.0f;
            #pragma unroll
            for (int c = 0; c < 8; c++){
                int drow = c * 16 + fr;
                f16x8 bf = *(const f16x8*)&lD[drow * 64 + (((h * 4 + q) ^ (drow & 7)) * 8)];
                acc[c] = __builtin_amdgcn_mfma_f32_16x16x32_f16(af, bf, acc[c], 0, 0, 0);
            }
        }
    };

    loadg(0); stage(0); __syncthreads();
    for (int c = 0; c < 32; c++){
        if (c + 1 < 32) loadg((c + 1) * 64);
        compute(c & 1);
        if (c + 1 < 32) stage((c + 1) & 1);
        __syncthreads();
    }

    // Phase 2: Q (f16, per-wave-private rows) @ Wc^T via MFMA.
    _Float16* sQ = (_Float16*)smem;
    #pragma unroll
    for (int c = 0; c < 8; c++){
        #pragma unroll
        for (int reg = 0; reg < 4; reg++){
            int row = w * 16 + q * 4 + reg;
            int col = c * 16 + fr;
            sQ[row * 128 + (((col >> 3) ^ (row & 7)) * 8) + (col & 7)] = (_Float16)acc[c][reg];
        }
    }
    f32x4 acc2[8] = {};
    #pragma unroll
    for (int kk = 0; kk < 4; kk++){
        int arow = w * 16 + fr;
        f16x8 a2 = *(const f16x8*)&sQ[arow * 128 + (((kk * 4 + q) ^ (arow & 7)) * 8)];
        #pragma unroll
        for (int c = 0; c < 8; c++){
            int n = c * 16 + fr;
            f16x8 b2 = *(const f16x8*)&lWc[n * 128 + (((kk * 4 + q) ^ (n & 7)) * 8)];
            acc2[c] = __builtin_amdgcn_mfma_f32_16x16x32_f16(a2, b2, acc2[c], 0, 0, 0);
        }
    }
    __syncthreads();
    float* sD = (float*)smem;
    #pragma unroll
    for (int c = 0; c < 8; c++)
        #pragma unroll
        for (int reg = 0; reg < 4; reg++)
            sD[(w * 16 + q * 4 + reg) * 132 + c * 16 + fr] = acc2[c][reg];
    __syncthreads();
    #pragma unroll
    for (int i = 0; i < 8; i++){
        int idx = t + 256 * i;
        int lrow = idx >> 5, c4 = idx & 31;
        float4 v = *(const float4*)&sD[lrow * 132 + c4 * 4];
        *(float4*)(op + (size_t)lrow * 128 + c4 * 4) = v;
    }
}

// ---------------------------------------------------------------------------
// rowmm_sum4: A = p0+p1+p2+p3; A -> aggOut (aliases p0, safe) and
// C = A @ W^T -> C.
// ---------------------------------------------------------------------------
__global__ __launch_bounds__(256) void rowmm_sum4(const float* __restrict__ p,
                                                  const float* __restrict__ W,
                                                  float* aggOut,
                                                  float* __restrict__ C)
{
    __shared__ alignas(16) float lA[32][132];
    __shared__ alignas(16) float lW[64][140];
    const int t = threadIdx.x;
    const int row0 = blockIdx.x * 32;
    const float4* P4 = (const float4*)p;
    const float4* W4 = (const float4*)W;
    float4* A4 = (float4*)aggOut;
    const size_t SS = 2097152 / 4;

    #pragma unroll
    for (int i = 0; i < 4; i++){
        int idx = t + 256 * i;
        int r = idx >> 5, k4 = idx & 31;
        size_t gi = (size_t)(row0 + r) * 32 + k4;
        float4 a = P4[gi], b = P4[gi + SS], c = P4[gi + 2 * SS], d = P4[gi + 3 * SS];
        float4 s = make_float4(a.x + b.x + c.x + d.x, a.y + b.y + c.y + d.y,
                               a.z + b.z + c.z + d.z, a.w + b.w + c.w + d.w);
        *(float4*)&lA[r][k4 * 4] = s;
        A4[gi] = s;
    }
    const int qq = t >> 5, cc = t & 31;

    #pragma unroll
    for (int ph = 0; ph < 2; ph++){
        __syncthreads();
        #pragma unroll
        for (int i = 0; i < 8; i++){
            int idx = t + 256 * i;
            int c = idx >> 5, k4 = idx & 31;
            *(float4*)&lW[c][k4 * 4] = W4[(size_t)(ph * 64 + c) * 32 + k4];
        }
        __syncthreads();
        float s[4][2] = {};
        for (int k4 = 0; k4 < 32; k4++){
            float4 w0 = *(const float4*)&lW[cc][k4 * 4];
            float4 w1 = *(const float4*)&lW[cc + 32][k4 * 4];
            #pragma unroll
            for (int j = 0; j < 4; j++){
                float4 a = *(const float4*)&lA[qq + 8 * j][k4 * 4];
                s[j][0] += a.x * w0.x + a.y * w0.y + a.z * w0.z + a.w * w0.w;
                s[j][1] += a.x * w1.x + a.y * w1.y + a.z * w1.z + a.w * w1.w;
            }
        }
        #pragma unroll
        for (int j = 0; j < 4; j++){
            size_t ro = (size_t)(row0 + qq + 8 * j) * DD + ph * 64;
            C[ro + cc]      = s[j][0];
            C[ro + cc + 32] = s[j][1];
        }
    }
}

// ---------------------------------------------------------------------------
// rowmm: C[n,:] = A[n,:] @ W^T, fp32.
// ---------------------------------------------------------------------------
__global__ __launch_bounds__(256) void rowmm(const float* A,
                                             const float* __restrict__ W,
                                             float* C)
{
    __shared__ alignas(16) float lA[32][132];
    __shared__ alignas(16) float lW[64][140];
    const int t = threadIdx.x;
    const int row0 = blockIdx.x * 32;
    const float4* A4 = (const float4*)A;
    const float4* W4 = (const float4*)W;

    #pragma unroll
    for (int i = 0; i < 4; i++){
        int idx = t + 256 * i;
        int r = idx >> 5, k4 = idx & 31;
        *(float4*)&lA[r][k4 * 4] = A4[(size_t)(row0 + r) * 32 + k4];
    }
    const int qq = t >> 5, cc = t & 31;

    #pragma unroll
    for (int ph = 0; ph < 2; ph++){
        __syncthreads();
        #pragma unroll
        for (int i = 0; i < 8; i++){
            int idx = t + 256 * i;
            int c = idx >> 5, k4 = idx & 31;
            *(float4*)&lW[c][k4 * 4] = W4[(size_t)(ph * 64 + c) * 32 + k4];
        }
        __syncthreads();
        float s[4][2] = {};
        for (int k4 = 0; k4 < 32; k4++){
            float4 w0 = *(const float4*)&lW[cc][k4 * 4];
            float4 w1 = *(const float4*)&lW[cc + 32][k4 * 4];
            #pragma unroll
            for (int j = 0; j < 4; j++){
                float4 a = *(const float4*)&lA[qq + 8 * j][k4 * 4];
                s[j][0] += a.x * w0.x + a.y * w0.y + a.z * w0.z + a.w * w0.w;
                s[j][1] += a.x * w1.x + a.y * w1.y + a.z * w1.z + a.w * w1.w;
            }
        }
        #pragma unroll
        for (int j = 0; j < 4; j++){
            size_t ro = (size_t)(row0 + qq + 8 * j) * DD + ph * 64;
            C[ro + cc]      = s[j][0];
            C[ro + cc + 32] = s[j][1];
        }
    }
}

// ---------------------------------------------------------------------------
// wc_mm16: Wc16 = f16(eWp @ vWp)  (128x128x128)
// ---------------------------------------------------------------------------
__global__ __launch_bounds__(256) void wc_mm16(const float* __restrict__ eWp,
                                               const float* __restrict__ vWp,
                                               _Float16* __restrict__ Wc16)
{
    int i = blockIdx.x * 2 + (threadIdx.x >> 7);
    int j = threadIdx.x & 127;
    float acc = 0.f;
    for (int k = 0; k < 128; k++)
        acc += eWp[i * 128 + k] * vWp[k * 128 + j];
    Wc16[i * 128 + j] = (_Float16)acc;
}

// ---------------------------------------------------------------------------
// Online softmax over e (two passes, coalesced).
// ---------------------------------------------------------------------------
__global__ __launch_bounds__(256) void sm_part(const float* __restrict__ eatt,
                                               float* __restrict__ part)
{
    const int b = blockIdx.x, slab = blockIdx.y;
    const int t = threadIdx.x;
    const int dl = t & 127, eh = t >> 7;
    const size_t base = (size_t)b * EE * DD + dl;
    const int e0 = slab * 256;
    float m = -1e30f;
    for (int s = 0; s < 128; s++)
        m = fmaxf(m, eatt[base + (size_t)(e0 + eh + 2 * s) * DD]);
    float l = 0.f;
    for (int s = 0; s < 128; s++)
        l += __expf(eatt[base + (size_t)(e0 + eh + 2 * s) * DD] - m);
    __shared__ float red[2][128][2];
    red[eh][dl][0] = m; red[eh][dl][1] = l;
    __syncthreads();
    if (t < 128){
        float m0 = red[0][t][0], l0 = red[0][t][1];
        float m1 = red[1][t][0], l1 = red[1][t][1];
        float M = fmaxf(m0, m1);
        float L = l0 * __expf(m0 - M) + l1 * __expf(m1 - M);
        float* pp = part + ((size_t)(b * 8 + slab) * DD + t) * 2;
        pp[0] = M; pp[1] = L;
    }
}

__global__ __launch_bounds__(256) void sm_apply(float* __restrict__ eatt,
                                                const float* __restrict__ agg,
                                                const float* __restrict__ part)
{
    const int b = blockIdx.x, sl = blockIdx.y;
    const int t = threadIdx.x;
    __shared__ float mv[128], iv[128];
    if (t < 128){
        float mbuf[8], lbuf[8];
        float M = -1e30f;
        #pragma unroll
        for (int s = 0; s < 8; s++){
            const float* pp = part + ((size_t)(b * 8 + s) * DD + t) * 2;
            mbuf[s] = pp[0]; lbuf[s] = pp[1];
            M = fmaxf(M, mbuf[s]);
        }
        float L = 0.f;
        #pragma unroll
        for (int s = 0; s < 8; s++) L += lbuf[s] * __expf(mbuf[s] - M);
        mv[t] = M; iv[t] = 1.f / L;
    }
    __syncthreads();
    const int dl = t & 127, eh = t >> 7;
    const size_t base = (size_t)b * EE * DD + dl;
    const int e0 = sl * 128;
    for (int s = 0; s < 64; s++){
        size_t ix = base + (size_t)(e0 + eh + 2 * s) * DD;
        eatt[ix] = agg[ix] * __expf(eatt[ix] - mv[dl]) * iv[dl];
    }
}

// ---------------------------------------------------------------------------
// Pipeline (layer recursion = fixed point; ec_Wa dead):
//  1. featT = T(feat) f16 ; Wc16 = f16(eWp@vWp)
//  2. fused_gemm1: ONE inc pass -> p0..p3 (split-K agg) + bitsX
//  3. agg = sum p ; eatt = agg@vWa^T (fused)
//  4. softmax -> P (in-place)
//  5. edge = P@vWp^T (OUT2); PT = T(P) f16
//  6. node = (inc@P)@Wc^T fused bitgemm2 (OUT1)
// ws: [0,8M)=bitsX; [8,40M)=p0..p3 (agg over p0, PT over p1); [40M)=Wc16.
// d_out: node[0,8M)=featT; node[8,16M)=eatt/P; edge=part->edge.
// ---------------------------------------------------------------------------
extern "C" void kernel_launch(void* const* d_in, const int* in_sizes, int n_in,
                              void* d_out, int out_size, void* d_ws, size_t ws_size,
                              hipStream_t stream)
{
    const float* feat = (const float*)d_in[0];
    const float* inc  = (const float*)d_in[1];
    const float* vWa  = (const float*)d_in[2];
    const float* vWp  = (const float*)d_in[3];
    const float* eWp  = (const float*)d_in[6];

    float* node_out = (float*)d_out;
    float* edge_out = node_out + (size_t)BB * MM * DD;

    char* w = (char*)d_ws;
    unsigned long long* bitsX = (unsigned long long*)w;        // [0,8M)
    float* pk  = (float*)(w + ((size_t)8 << 20));              // p0..p3 (8 MB each)
    float* agg = pk;                                           // over p0
    _Float16* PT = (_Float16*)(w + ((size_t)16 << 20));        // over p1 (dead after sum4)
    _Float16* Wc16 = (_Float16*)(w + ((size_t)40 << 20));

    _Float16* featT = (_Float16*)node_out;                     // node[0,8M)
    float* eattP = node_out + 2097152;                         // node[8,16M)
    float* part  = edge_out;                                   // dead before edge

    dim3 blk(256);

    // 1. featT + Wc16
    transpose_to16<<<dim3((MM / 64) * (DD / 64), BB), blk, 0, stream>>>(feat, featT, MM, DD);
    wc_mm16<<<dim3(64), blk, 0, stream>>>(eWp, vWp, Wc16);
    // 2. one inc pass: p partials + bitsX
    fused_gemm1<<<dim3(EE / 256, BB, 4), blk, 0, stream>>>(inc, featT, bitsX, pk);
    // 3. agg = sum p ; eatt = agg @ vWa^T
    rowmm_sum4<<<dim3(BB * EE / 32), blk, 0, stream>>>(pk, vWa, agg, eattP);
    // 4. P = agg * softmax_e(eatt)
    sm_part <<<dim3(BB, 8),  blk, 0, stream>>>(eattP, part);
    sm_apply<<<dim3(BB, 16), blk, 0, stream>>>(eattP, agg, part);
    // 5. edge = P @ vWp^T (OUT2); PT = f16(P^T)
    rowmm<<<dim3(BB * EE / 32), blk, 0, stream>>>(eattP, vWp, edge_out);
    transpose_to16<<<dim3((EE / 64) * (DD / 64), BB), blk, 0, stream>>>(eattP, PT, EE, DD);
    // 6. node = (inc@P) @ Wc^T fused (OUT1)
    bitgemm2_fused<<<dim3(MM / 64, BB), blk, 0, stream>>>(bitsX, PT, Wc16, node_out);
}